// Round 1
// baseline (1229.086 us; speedup 1.0000x reference)
//
#include <hip/hip_runtime.h>
#include <hip/hip_bf16.h>

typedef __bf16 bf16_t;
typedef bf16_t bf16x8 __attribute__((ext_vector_type(8)));
typedef bf16_t bf16x4 __attribute__((ext_vector_type(4)));
typedef float  f32x4  __attribute__((ext_vector_type(4)));

static_assert(sizeof(bf16x8) == 16, "bf16x8 must be 16B");

// ---------------------------------------------------------------------------
// ws layout (bytes):
//   0      : Wqkv_t bf16 [576][192]  (221184)  n-major: row n = output col, k contiguous
//   221184 : Wp_t   bf16 [192][192]  ( 73728)
//   294912 : b_qkv  f32  [576]       (  2304)
//   297216 : bias6  f32  [6][49][49] ( 57624)
// ---------------------------------------------------------------------------

__global__ __launch_bounds__(256) void swin_prep(
    const float* __restrict__ Wq, const float* __restrict__ bq,
    const float* __restrict__ Wk, const float* __restrict__ bk,
    const float* __restrict__ Wv, const float* __restrict__ bv,
    const float* __restrict__ Wp,
    const float* __restrict__ rel_bias, const int* __restrict__ pos_index,
    bf16_t* __restrict__ Wqkv_t, bf16_t* __restrict__ Wp_t,
    float* __restrict__ b_qkv, float* __restrict__ bias6)
{
    int i = blockIdx.x * blockDim.x + threadIdx.x;
    if (i < 110592) {                       // Wqkv_t[n][k] = W*[k][n']
        int n = i / 192, k = i % 192;
        float v;
        if (n < 192)      v = Wq[k*192 + n];
        else if (n < 384) v = Wk[k*192 + (n-192)];
        else              v = Wv[k*192 + (n-384)];
        Wqkv_t[i] = (bf16_t)v;
    } else if (i < 147456) {                // Wp_t[n][k] = Wp[k][n]
        int j = i - 110592;
        int n = j / 192, k = j % 192;
        Wp_t[j] = (bf16_t)Wp[k*192 + n];
    } else if (i < 148032) {                // fused qkv bias
        int c = i - 147456;
        b_qkv[c] = (c < 192) ? bq[c] : (c < 384 ? bk[c-192] : bv[c-384]);
    } else if (i < 162438) {                // bias6[h][i][j] = rel_bias[pos_index[i][j]][h]
        int j = i - 148032;
        int h = j / 2401, rc = j % 2401;
        bias6[j] = rel_bias[pos_index[rc]*6 + h];
    }
}

// ---------------------------------------------------------------------------
// Fused window attention: 1 block = 1 window (49 tokens, 192 dim, 6 heads x 32)
// 512 threads = 8 waves.
// MFMA 16x16x32 bf16 layouts (verified per guide):
//   A: row = lane&15,            k = (lane>>4)*8 + r   (8 contiguous bf16 = 16B)
//   B: col = lane&15,            k = (lane>>4)*8 + r
//   C/D: col = lane&15,          row = (lane>>4)*4 + i
// ---------------------------------------------------------------------------

__global__ __launch_bounds__(512) void swin_attn(
    const float* __restrict__ x, const float* __restrict__ mask,
    const float* __restrict__ bp,
    const bf16_t* __restrict__ Wqkv_t, const bf16_t* __restrict__ Wp_t,
    const float* __restrict__ b_qkv, const float* __restrict__ bias6,
    float* __restrict__ out)
{
    // strides chosen: byte-stride %16 == 0 (b128 alignment), (stride/4)%32 in {2,4}
    // -> <=2-way LDS bank aliasing (free).
    __shared__ __align__(16) bf16_t xb[64][200];     // x (stage A/B), then O (stage D/E)
    __shared__ __align__(16) bf16_t qkb[64][392];    // q: cols 0..191, k: cols 192..383
    __shared__ __align__(16) bf16_t vT[6][32][72];   // per-head transposed V: vT[h][d][token]
    __shared__ __align__(16) bf16_t Pb[8][16][72];   // per-wave softmax P tile (16 x 64, padded)

    const int b    = blockIdx.x;
    const int win  = b & 1023;               // b = outer*1024 + win
    const int tid  = threadIdx.x;
    const int wave = tid >> 6;
    const int lane = tid & 63;
    const int lq   = lane & 15;
    const int lg   = lane >> 4;

    // ---- Stage A: load x window -> LDS bf16; zero pad rows 49..63 ----
    {
        const float4* xw = reinterpret_cast<const float4*>(x + (size_t)b * 9408);
        #pragma unroll
        for (int it = 0; it < 5; ++it) {
            int i = tid + it * 512;
            if (i < 2352) {                      // 2352 float4 = 49*192 floats
                float4 f = xw[i];
                int r = i / 48, c = (i % 48) * 4; // 48 float4 per row
                bf16x4 o = { (bf16_t)f.x, (bf16_t)f.y, (bf16_t)f.z, (bf16_t)f.w };
                *reinterpret_cast<bf16x4*>(&xb[r][c]) = o;
            }
        }
        for (int i = tid; i < 3000; i += 512)    // 15 rows * 200
            xb[49 + i/200][i%200] = (bf16_t)0.f;
    }
    __syncthreads();

    // ---- Stage B: qkv = x @ Wqkv + b  (M=49->64, N=576, K=192) ----
    for (int nt = wave; nt < 36; nt += 8) {
        const int cn = nt*16 + lq;                       // output column 0..575
        f32x4 acc0 = {0.f,0.f,0.f,0.f}, acc1 = acc0, acc2 = acc0, acc3 = acc0;
        #pragma unroll
        for (int k6 = 0; k6 < 6; ++k6) {
            bf16x8 bf = *reinterpret_cast<const bf16x8*>(&Wqkv_t[cn*192 + k6*32 + lg*8]);
            bf16x8 a0 = *reinterpret_cast<const bf16x8*>(&xb[ 0 + lq][k6*32 + lg*8]);
            bf16x8 a1 = *reinterpret_cast<const bf16x8*>(&xb[16 + lq][k6*32 + lg*8]);
            bf16x8 a2 = *reinterpret_cast<const bf16x8*>(&xb[32 + lq][k6*32 + lg*8]);
            bf16x8 a3 = *reinterpret_cast<const bf16x8*>(&xb[48 + lq][k6*32 + lg*8]);
            acc0 = __builtin_amdgcn_mfma_f32_16x16x32_bf16(a0, bf, acc0, 0, 0, 0);
            acc1 = __builtin_amdgcn_mfma_f32_16x16x32_bf16(a1, bf, acc1, 0, 0, 0);
            acc2 = __builtin_amdgcn_mfma_f32_16x16x32_bf16(a2, bf, acc2, 0, 0, 0);
            acc3 = __builtin_amdgcn_mfma_f32_16x16x32_bf16(a3, bf, acc3, 0, 0, 0);
        }
        const float bias = b_qkv[cn];
        if (cn < 384) {                                  // q or k: row-major into qkb
            #pragma unroll
            for (int i = 0; i < 4; ++i) {
                qkb[ 0 + lg*4 + i][cn] = (bf16_t)(acc0[i] + bias);
                qkb[16 + lg*4 + i][cn] = (bf16_t)(acc1[i] + bias);
                qkb[32 + lg*4 + i][cn] = (bf16_t)(acc2[i] + bias);
                qkb[48 + lg*4 + i][cn] = (bf16_t)(acc3[i] + bias);
            }
        } else {                                         // v: transposed into vT[h][d][token]
            const int h = (cn - 384) >> 5, c = (cn - 384) & 31;
            #pragma unroll
            for (int i = 0; i < 4; ++i) {
                vT[h][c][ 0 + lg*4 + i] = (bf16_t)(acc0[i] + bias);
                vT[h][c][16 + lg*4 + i] = (bf16_t)(acc1[i] + bias);
                vT[h][c][32 + lg*4 + i] = (bf16_t)(acc2[i] + bias);
                vT[h][c][48 + lg*4 + i] = (bf16_t)(acc3[i] + bias);
            }
        }
    }
    __syncthreads();

    // ---- Stage C/D: per (head, m-tile): S = qk^T, softmax(+bias+mask), O = P@V ----
    const float scale = 0.17677669529663687f;            // 32^-0.5
    for (int p = wave; p < 24; p += 8) {
        const int h = p >> 2;
        const int m = p & 3;
        // S = q @ k^T : A = q rows of this m-tile, B[kk][n] = K[n][kk] (contiguous reads)
        bf16x8 qf = *reinterpret_cast<const bf16x8*>(&qkb[m*16 + lq][h*32 + lg*8]);
        f32x4 z = {0.f,0.f,0.f,0.f};
        bf16x8 k0 = *reinterpret_cast<const bf16x8*>(&qkb[ 0 + lq][192 + h*32 + lg*8]);
        bf16x8 k1 = *reinterpret_cast<const bf16x8*>(&qkb[16 + lq][192 + h*32 + lg*8]);
        bf16x8 k2 = *reinterpret_cast<const bf16x8*>(&qkb[32 + lq][192 + h*32 + lg*8]);
        bf16x8 k3 = *reinterpret_cast<const bf16x8*>(&qkb[48 + lq][192 + h*32 + lg*8]);
        f32x4 s0 = __builtin_amdgcn_mfma_f32_16x16x32_bf16(qf, k0, z, 0, 0, 0);
        f32x4 s1 = __builtin_amdgcn_mfma_f32_16x16x32_bf16(qf, k1, z, 0, 0, 0);
        f32x4 s2 = __builtin_amdgcn_mfma_f32_16x16x32_bf16(qf, k2, z, 0, 0, 0);
        f32x4 s3 = __builtin_amdgcn_mfma_f32_16x16x32_bf16(qf, k3, z, 0, 0, 0);

        const float* biasH = bias6 + h * 2401;
        const float* maskW = mask + (size_t)win * 2401;
        #pragma unroll
        for (int i = 0; i < 4; ++i) {
            const int row   = m*16 + lg*4 + i;
            const bool rowok = (row < 49);
            const int rbase = row * 49;
            // cols: lq, 16+lq, 32+lq, 48+lq (last valid only for lq==0)
            float sv0 = rowok ? (s0[i]*scale + biasH[rbase +      lq] + maskW[rbase +      lq]) : -1e30f;
            float sv1 = rowok ? (s1[i]*scale + biasH[rbase + 16 + lq] + maskW[rbase + 16 + lq]) : -1e30f;
            float sv2 = rowok ? (s2[i]*scale + biasH[rbase + 32 + lq] + maskW[rbase + 32 + lq]) : -1e30f;
            float sv3 = (rowok && lq == 0)
                      ? (s3[i]*scale + biasH[rbase + 48] + maskW[rbase + 48]) : -1e30f;
            // row max across 16-lane column group
            float mx = fmaxf(fmaxf(sv0, sv1), fmaxf(sv2, sv3));
            mx = fmaxf(mx, __shfl_xor(mx, 1));
            mx = fmaxf(mx, __shfl_xor(mx, 2));
            mx = fmaxf(mx, __shfl_xor(mx, 4));
            mx = fmaxf(mx, __shfl_xor(mx, 8));
            float e0 = __expf(sv0 - mx), e1 = __expf(sv1 - mx);
            float e2 = __expf(sv2 - mx), e3 = __expf(sv3 - mx);
            float sum = e0 + e1 + e2 + e3;
            sum += __shfl_xor(sum, 1);
            sum += __shfl_xor(sum, 2);
            sum += __shfl_xor(sum, 4);
            sum += __shfl_xor(sum, 8);
            const float inv = 1.0f / sum;                // sum>=1 for valid rows, 64 for pad rows
            const int lr = lg*4 + i;
            Pb[wave][lr][     lq] = (bf16_t)(rowok ? e0 * inv : 0.f);
            Pb[wave][lr][16 + lq] = (bf16_t)(rowok ? e1 * inv : 0.f);
            Pb[wave][lr][32 + lq] = (bf16_t)(rowok ? e2 * inv : 0.f);
            Pb[wave][lr][48 + lq] = (bf16_t)((rowok && lq == 0) ? e3 * inv : 0.f);
        }
        // O_mtile = P @ V : A = P (wave-private), B[kk][n] = V[kk][n] = vT[n][kk]
        f32x4 o0 = {0.f,0.f,0.f,0.f}, o1 = o0;
        #pragma unroll
        for (int ks = 0; ks < 2; ++ks) {
            bf16x8 pf = *reinterpret_cast<const bf16x8*>(&Pb[wave][lq][ks*32 + lg*8]);
            bf16x8 v0 = *reinterpret_cast<const bf16x8*>(&vT[h][     lq][ks*32 + lg*8]);
            bf16x8 v1 = *reinterpret_cast<const bf16x8*>(&vT[h][16 + lq][ks*32 + lg*8]);
            o0 = __builtin_amdgcn_mfma_f32_16x16x32_bf16(pf, v0, o0, 0, 0, 0);
            o1 = __builtin_amdgcn_mfma_f32_16x16x32_bf16(pf, v1, o1, 0, 0, 0);
        }
        #pragma unroll
        for (int i = 0; i < 4; ++i) {                    // O into xb (x no longer needed)
            xb[m*16 + lg*4 + i][h*32 +      lq] = (bf16_t)o0[i];
            xb[m*16 + lg*4 + i][h*32 + 16 + lq] = (bf16_t)o1[i];
        }
    }
    __syncthreads();

    // ---- Stage E: out = O @ Wp + bp  (M=49->64, N=192, K=192) ----
    float* outw = out + (size_t)b * 9408;
    for (int nt = wave; nt < 12; nt += 8) {
        const int cn = nt*16 + lq;
        f32x4 acc0 = {0.f,0.f,0.f,0.f}, acc1 = acc0, acc2 = acc0, acc3 = acc0;
        #pragma unroll
        for (int k6 = 0; k6 < 6; ++k6) {
            bf16x8 bf = *reinterpret_cast<const bf16x8*>(&Wp_t[cn*192 + k6*32 + lg*8]);
            bf16x8 a0 = *reinterpret_cast<const bf16x8*>(&xb[ 0 + lq][k6*32 + lg*8]);
            bf16x8 a1 = *reinterpret_cast<const bf16x8*>(&xb[16 + lq][k6*32 + lg*8]);
            bf16x8 a2 = *reinterpret_cast<const bf16x8*>(&xb[32 + lq][k6*32 + lg*8]);
            bf16x8 a3 = *reinterpret_cast<const bf16x8*>(&xb[48 + lq][k6*32 + lg*8]);
            acc0 = __builtin_amdgcn_mfma_f32_16x16x32_bf16(a0, bf, acc0, 0, 0, 0);
            acc1 = __builtin_amdgcn_mfma_f32_16x16x32_bf16(a1, bf, acc1, 0, 0, 0);
            acc2 = __builtin_amdgcn_mfma_f32_16x16x32_bf16(a2, bf, acc2, 0, 0, 0);
            acc3 = __builtin_amdgcn_mfma_f32_16x16x32_bf16(a3, bf, acc3, 0, 0, 0);
        }
        const float bias = bp[cn];
        #pragma unroll
        for (int i = 0; i < 4; ++i) {
            const int r = lg*4 + i;
            outw[(     r)*192 + cn] = acc0[i] + bias;
            outw[(16 + r)*192 + cn] = acc1[i] + bias;
            outw[(32 + r)*192 + cn] = acc2[i] + bias;
            if (48 + r < 49) outw[(48 + r)*192 + cn] = acc3[i] + bias;
        }
    }
}

extern "C" void kernel_launch(void* const* d_in, const int* in_sizes, int n_in,
                              void* d_out, int out_size, void* d_ws, size_t ws_size,
                              hipStream_t stream) {
    const float* x         = (const float*)d_in[0];
    const float* mask      = (const float*)d_in[1];
    const float* Wq        = (const float*)d_in[2];
    const float* bq        = (const float*)d_in[3];
    const float* Wk        = (const float*)d_in[4];
    const float* bk        = (const float*)d_in[5];
    const float* Wv        = (const float*)d_in[6];
    const float* bv        = (const float*)d_in[7];
    const float* Wp        = (const float*)d_in[8];
    const float* bp        = (const float*)d_in[9];
    const float* rel_bias  = (const float*)d_in[10];
    const int*   pos_index = (const int*)d_in[11];

    char* ws = (char*)d_ws;
    bf16_t* Wqkv_t = (bf16_t*)(ws + 0);
    bf16_t* Wp_t   = (bf16_t*)(ws + 221184);
    float*  b_qkv  = (float*) (ws + 294912);
    float*  bias6  = (float*) (ws + 297216);

    hipLaunchKernelGGL(swin_prep, dim3(635), dim3(256), 0, stream,
                       Wq, bq, Wk, bk, Wv, bv, Wp, rel_bias, pos_index,
                       Wqkv_t, Wp_t, b_qkv, bias6);
    hipLaunchKernelGGL(swin_attn, dim3(8192), dim3(512), 0, stream,
                       x, mask, bp, Wqkv_t, Wp_t, b_qkv, bias6, (float*)d_out);
}